// Round 4
// baseline (213.869 us; speedup 1.0000x reference)
//
#include <hip/hip_runtime.h>
#include <hip/hip_bf16.h>
#include <stdint.h>

// MultiheadSelfAttention: B=2, S=4096, D=512, H=8, HD=64
// v13: PV back to FULL-RATE K=32 MFMA without any cross-lane transpose.
// Key insight: MFMA contracts positionally (A elem j, quad q)x(B elem j, quad q),
// so P can sit at a PERMUTED k-placement pi(q,j) = concat(pb[2c],pb[2c+1])
// as long as V's A-fragment is read from LDS with the SAME permutation --
// which is exactly the two existing 8B voff reads concatenated. Halves PV
// MFMA issue count (32 K16 -> 16 K32); ones-l likewise (8 K16 -> 4 K32,
// valid since A=ones is k-permutation-invariant).
// v12's raw v_exp + setprio retained. GEMMs unchanged.

typedef __attribute__((ext_vector_type(8))) short short8;
typedef __attribute__((ext_vector_type(4))) short sv4;
typedef __attribute__((ext_vector_type(4))) float floatx4;

#define MFMA(a, b, c) __builtin_amdgcn_mfma_f32_16x16x32_bf16((a), (b), (c), 0, 0, 0)

typedef __attribute__((address_space(1))) const void* gas_t;
typedef __attribute__((address_space(3))) void* las_t;
#define GLDS16(g, l) __builtin_amdgcn_global_load_lds((gas_t)(g), (las_t)(l), 16, 0, 0)

#define SM_SHIFT 13.0f

__device__ __forceinline__ float fexp2(float x) {
#if __has_builtin(__builtin_amdgcn_exp2f)
    return __builtin_amdgcn_exp2f(x);      // bare v_exp_f32
#else
    float r;
    asm("v_exp_f32 %0, %1" : "=v"(r) : "v"(x));
    return r;
#endif
}

__device__ __forceinline__ short f2bf(float f) {
    union { float f; uint32_t u; } c; c.f = f;
    uint32_t u = c.u;
    u += 0x7fffu + ((u >> 16) & 1u);   // RNE
    return (short)(u >> 16);
}
__device__ __forceinline__ float bf2f(short s) {
    union { float f; uint32_t u; } c; c.u = ((uint32_t)(uint16_t)s) << 16;
    return c.f;
}
__device__ __forceinline__ int pack2(float a, float b) {
    return (int)(uint16_t)f2bf(a) | ((int)(uint16_t)f2bf(b) << 16);
}
// bf16 pack of two floats: 1 instr on gfx950 if builtin exists, else 3.
__device__ __forceinline__ int pack2rn(float a, float b) {
#if __has_builtin(__builtin_amdgcn_cvt_pk_bf16_f32)
    auto r = __builtin_amdgcn_cvt_pk_bf16_f32(a, b);
    int out; __builtin_memcpy(&out, &r, 4);
    return out;
#else
    union { float f; uint32_t u; } x, y; x.f = a; y.f = b;
    return __builtin_amdgcn_perm(y.u + 0x8000u, x.u + 0x8000u, 0x07060302);
#endif
}

// ---------------------------------------------------------------- converts
__global__ void cvt_bf16(const float* __restrict__ src, short* __restrict__ dst, int n) {
    int i = (blockIdx.x * 256 + threadIdx.x) * 8;
    if (i >= n) return;
    floatx4 v0 = *(const floatx4*)(src + i);
    floatx4 v1 = *(const floatx4*)(src + i + 4);
    short8 o;
    #pragma unroll
    for (int j = 0; j < 4; ++j) { o[j] = f2bf(v0[j]); o[4 + j] = f2bf(v1[j]); }
    *(short8*)(dst + i) = o;
}

__global__ void cvt3_bf16(const float* __restrict__ s0, const float* __restrict__ s1,
                          const float* __restrict__ s2, short* __restrict__ d0,
                          short* __restrict__ d1, short* __restrict__ d2) {
    int idx = blockIdx.x * 256 + threadIdx.x;
    int which = idx >> 15;
    int i = (idx & 32767) * 8;
    const float* src = which == 0 ? s0 : which == 1 ? s1 : s2;
    short* dst = which == 0 ? d0 : which == 1 ? d1 : d2;
    floatx4 v0 = *(const floatx4*)(src + i);
    floatx4 v1 = *(const floatx4*)(src + i + 4);
    short8 o;
    #pragma unroll
    for (int j = 0; j < 4; ++j) { o[j] = f2bf(v0[j]); o[4 + j] = f2bf(v1[j]); }
    *(short8*)(dst + i) = o;
}

__global__ void cvt_split(const float* __restrict__ src, short* __restrict__ hi,
                          short* __restrict__ lo, int n) {
    int i = (blockIdx.x * 256 + threadIdx.x) * 8;
    if (i >= n) return;
    floatx4 v0 = *(const floatx4*)(src + i);
    floatx4 v1 = *(const floatx4*)(src + i + 4);
    short8 h, l;
    #pragma unroll
    for (int j = 0; j < 4; ++j) {
        short hh = f2bf(v0[j]); h[j] = hh; l[j] = f2bf(v0[j] - bf2f(hh));
        short hh1 = f2bf(v1[j]); h[4 + j] = hh1; l[4 + j] = f2bf(v1[j] - bf2f(hh1));
    }
    *(short8*)(hi + i) = h;
    *(short8*)(lo + i) = l;
}

// ---------------------------------------------------------------- QKV GEMM
__global__ __launch_bounds__(256) void qkv_gemm(
    const short* __restrict__ Xb,
    const short* __restrict__ Wq, const short* __restrict__ Wk, const short* __restrict__ Wv,
    const float* __restrict__ bq, const float* __restrict__ bk, const float* __restrict__ bv,
    short* __restrict__ Qo, short* __restrict__ Ko, short* __restrict__ VTo)
{
    __shared__ short SMEM[16384];                 // 32 KB
    #define ASH(bf) (SMEM + (bf) * 4096)
    #define BSH(bf) (SMEM + 8192 + (bf) * 4096)
    const int lane = threadIdx.x & 63, wave = threadIdx.x >> 6;
    const int col = lane & 15, quad = lane >> 4;
    const int wm = wave & 1, wn = wave >> 1;
    const int m0 = blockIdx.x * 128;
    const int by = blockIdx.y;
    const int which = by >> 2;                    // 0=Q,1=K,2=V
    const int n0 = (by & 3) * 128;
    const short* W = which == 0 ? Wq : which == 1 ? Wk : Wv;
    const float* bias = which == 0 ? bq : which == 1 ? bk : bv;
    const float oscale = which == 0 ? 0.1803368801111204f : 1.0f;  // 0.125*log2e

    const int rl = lane >> 2, pch = lane & 3;
    const int lch = pch ^ (rl & 3) ^ ((rl >> 2) & 3);
    const int seg = wave * 2;
    const short* ag0 = Xb + (size_t)(m0 + seg * 16 + rl) * 512 + lch * 8;
    const short* ag1 = ag0 + (size_t)16 * 512;
    const short* bg0 = W + (size_t)(n0 + seg * 16 + rl) * 512 + lch * 8;
    const short* bg1 = bg0 + (size_t)16 * 512;

    floatx4 acc[4][4] = {};

    GLDS16(ag0, ASH(0) + seg * 512);
    GLDS16(ag1, ASH(0) + (seg + 1) * 512);
    GLDS16(bg0, BSH(0) + seg * 512);
    GLDS16(bg1, BSH(0) + (seg + 1) * 512);
    __syncthreads();

    for (int t = 0; t < 16; ++t) {
        const int cur = t & 1;
        if (t < 15) {
            const int kb = (t + 1) * 32;
            GLDS16(ag0 + kb, ASH(cur ^ 1) + seg * 512);
            GLDS16(ag1 + kb, ASH(cur ^ 1) + (seg + 1) * 512);
            GLDS16(bg0 + kb, BSH(cur ^ 1) + seg * 512);
            GLDS16(bg1 + kb, BSH(cur ^ 1) + (seg + 1) * 512);
        }
        short8 af[4], bf[4];
        #pragma unroll
        for (int it = 0; it < 4; ++it) {
            const int rA = wm * 64 + it * 16 + col;
            const int pA = quad ^ (rA & 3) ^ ((rA >> 2) & 3);
            af[it] = *(const short8*)(ASH(cur) + rA * 32 + pA * 8);
            const int rB = wn * 64 + it * 16 + col;
            const int pB = quad ^ (rB & 3) ^ ((rB >> 2) & 3);
            bf[it] = *(const short8*)(BSH(cur) + rB * 32 + pB * 8);
        }
        #pragma unroll
        for (int i = 0; i < 4; ++i)
            #pragma unroll
            for (int j = 0; j < 4; ++j)
                acc[i][j] = MFMA(af[i], bf[j], acc[i][j]);
        __syncthreads();
    }

    if (which < 2) {
        #pragma unroll
        for (int i = 0; i < 4; ++i)
            #pragma unroll
            for (int j = 0; j < 4; ++j)
                #pragma unroll
                for (int r = 0; r < 4; ++r) {
                    int m = m0 + wm * 64 + i * 16 + quad * 4 + r;
                    int n = n0 + wn * 64 + j * 16 + col;
                    float v = (acc[i][j][r] + bias[n]) * oscale;
                    int b = m >> 12, s = m & 4095;
                    int h = n >> 6, hd = n & 63;
                    int bh = b * 8 + h;
                    short bv16 = f2bf(v);
                    if (which == 0) Qo[((size_t)bh * 4096 + s) * 64 + hd] = bv16;
                    else            Ko[((size_t)bh * 4096 + s) * 64 + hd] = bv16;
                }
    } else {
        // V: per-wave LDS transpose (post-barrier, staging LDS is dead)
        short* tb = SMEM + wave * 4096;
        #pragma unroll
        for (int n2 = 0; n2 < 2; ++n2) {
            #pragma unroll
            for (int jj = 0; jj < 2; ++jj) {
                const int j = n2 * 2 + jj;
                const int n_rel = jj * 16 + col;
                const float bv_ = bias[n0 + wn * 64 + j * 16 + col];
                #pragma unroll
                for (int i = 0; i < 4; ++i) {
                    const int m_rel = i * 16 + quad * 4;
                    *(int*)(tb + n_rel * 72 + m_rel) =
                        pack2(acc[i][j][0] + bv_, acc[i][j][1] + bv_);
                    *(int*)(tb + n_rel * 72 + m_rel + 2) =
                        pack2(acc[i][j][2] + bv_, acc[i][j][3] + bv_);
                }
            }
            asm volatile("s_waitcnt lgkmcnt(0)" ::: "memory");  // wave-local
            const int n_rel = lane & 31, half = lane >> 5;
            const int n = n0 + wn * 64 + n2 * 32 + n_rel;
            const int h = n >> 6, hd = n & 63;
            const int bh = (m0 >> 12) * 8 + h;
            const int s0 = (m0 & 4095) + wm * 64 + half * 32;
            const short* src = tb + n_rel * 72 + half * 32;
            short* dst = VTo + ((size_t)bh * 64 + hd) * 4096 + s0;
            #pragma unroll
            for (int c = 0; c < 4; ++c)
                *(int4*)(dst + c * 8) = *(const int4*)(src + c * 8);
        }
    }
    #undef ASH
    #undef BSH
}

// ---------------------------------------------------------------- flash attn
// Fixed-shift softmax; shift pre-folded into sa (QK^T seeded with C=-13).
// P packed to bf16 and CONCATENATED across nt pairs: position (q,j) in the
// K=32 B-operand holds key pi(q,j) = 4q+j (j<4) / 16+4q+(j-4) (j>=4) within
// the 32-k block. V's A-fragment is read from LDS with the SAME pi (the two
// 8B voff reads concatenated), so products pair correctly. l via K=32
// ones-MFMA (A=ones is k-permutation-invariant).
__device__ __forceinline__ void softmax_pk(
    const floatx4* sa, floatx4& lacc, short8 ones8, short8* pb)  // pb[2]
{
    #pragma unroll
    for (int c = 0; c < 2; ++c) {
        union { int i[4]; short8 s; } u;
        #pragma unroll
        for (int h = 0; h < 2; ++h) {          // nt = 2c+h
            float p0 = fexp2(sa[2 * c + h][0]);
            float p1 = fexp2(sa[2 * c + h][1]);
            float p2 = fexp2(sa[2 * c + h][2]);
            float p3 = fexp2(sa[2 * c + h][3]);
            u.i[2 * h]     = pack2rn(p0, p1);
            u.i[2 * h + 1] = pack2rn(p2, p3);
        }
        pb[c] = u.s;
        lacc = MFMA(ones8, u.s, lacc);   // l += column sums of this 32-k block
    }
}

__global__ __launch_bounds__(512, 4) void flash_attn(
    const short* __restrict__ Q, const short* __restrict__ Kk,
    const short* __restrict__ VT,
    short* __restrict__ Ahi, short* __restrict__ Alo)
{
    __shared__ float SMEMf[16384];               // 64 KB
    short* SMEM = (short*)SMEMf;
    const int lane = threadIdx.x & 63, wave = threadIdx.x >> 6;
    const int col = lane & 15, quad = lane >> 4;
    const int id = blockIdx.x;
    const int bh = (id & 7) * 2 + (id >> 8);     // 2 bh per XCD cluster
    const int bx = (id >> 3) & 31;
    const int b = bh >> 3, h = bh & 7;
    const int qw = wave & 3, kz = wave >> 2;
    const int q0 = bx * 128 + qw * 32;
    const int kbeg = kz * 2048;
    const size_t base = (size_t)bh * 4096 * 64;
    const size_t vbase = (size_t)bh * 64 * 4096;

    #define KOFF(z, f) (((z) * 2 + (f)) * 4096)
    #define VOFF(z, f) (16384 + ((z) * 2 + (f)) * 4096)

    const short* qptr = Q + base + (size_t)(q0 + col) * 64 + quad * 8;
    short8 qA0 = *(const short8*)(qptr);
    short8 qA1 = *(const short8*)(qptr + 32);
    short8 qB0 = *(const short8*)(qptr + 16 * 64);
    short8 qB1 = *(const short8*)(qptr + 16 * 64 + 32);

    const int rloc = lane >> 3, pch = lane & 7;
    const int lch = pch ^ rloc;
    const short* kst0 = Kk + base + (size_t)(kbeg + qw * 16 + rloc) * 64 + lch * 8;
    const short* kst1 = kst0 + (size_t)8 * 64;
    const short* vst0 = VT + vbase + (size_t)(qw * 16 + rloc) * 4096 + kbeg + lch * 8;
    const short* vst1 = vst0 + (size_t)8 * 4096;

    floatx4 oA[4] = {}, oB[4] = {};
    floatx4 laccA = {0.f, 0.f, 0.f, 0.f}, laccB = {0.f, 0.f, 0.f, 0.f};
    const floatx4 mshift = {-SM_SHIFT, -SM_SHIFT, -SM_SHIFT, -SM_SHIFT};
    short8 ones8;
    #pragma unroll
    for (int j = 0; j < 8; ++j) ones8[j] = (short)0x3F80;   // bf16 1.0

    const int sw = col & 7;
    const int co0 = (quad ^ sw) * 8;
    const int co1 = ((quad + 4) ^ sw) * 8;
    // V fragment offsets: logical key = 16*nt + 4*quad within 64-key chunk;
    // 16B-chunk swizzle c_phys = c_log ^ (row&7), row&7 == col&7 == sw.
    int voff[4];
    #pragma unroll
    for (int nt = 0; nt < 4; ++nt)
        voff[nt] = ((2 * nt + (quad >> 1)) ^ sw) * 8 + (quad & 1) * 4;

    {
        short* kl = SMEM + KOFF(kz, 0) + (qw * 16) * 64;
        short* vl = SMEM + VOFF(kz, 0) + (qw * 16) * 64;
        GLDS16(kst0, kl);
        GLDS16(kst1, kl + 8 * 64);
        GLDS16(vst0, vl);
        GLDS16(vst1, vl + 8 * 64);
    }
    __syncthreads();

    for (int t = 0; t < 32; ++t) {
        const int cur = t & 1;
        if (t < 31) {
            const int kk2 = (t + 1) * 64;
            short* kl = SMEM + KOFF(kz, cur ^ 1) + (qw * 16) * 64;
            short* vl = SMEM + VOFF(kz, cur ^ 1) + (qw * 16) * 64;
            GLDS16(kst0 + (size_t)kk2 * 64, kl);
            GLDS16(kst1 + (size_t)kk2 * 64, kl + 8 * 64);
            GLDS16(vst0 + kk2, vl);
            GLDS16(vst1 + kk2, vl + 8 * 64);
        }
        floatx4 saA[4], saB[4];
        __builtin_amdgcn_s_setprio(1);
        #pragma unroll
        for (int nt = 0; nt < 4; ++nt) {
            const short* kr = SMEM + KOFF(kz, cur) + (nt * 16 + col) * 64;
            short8 k0 = *(const short8*)(kr + co0);
            short8 k1 = *(const short8*)(kr + co1);
            floatx4 z = MFMA(k0, qA0, mshift);       // seed C=-13: sa = S~ - 13
            saA[nt] = MFMA(k1, qA1, z);
            floatx4 z2 = MFMA(k0, qB0, mshift);
            saB[nt] = MFMA(k1, qB1, z2);
        }
        __builtin_amdgcn_s_setprio(0);
        short8 pbA[2], pbB[2];
        softmax_pk(saA, laccA, ones8, pbA);
        softmax_pk(saB, laccB, ones8, pbB);
        __builtin_amdgcn_s_setprio(1);
        #pragma unroll
        for (int mt = 0; mt < 4; ++mt) {
            const short* vr = SMEM + VOFF(kz, cur) + (mt * 16 + col) * 64;
            #pragma unroll
            for (int c = 0; c < 2; ++c) {
                union { sv4 h[2]; short8 s; } uv;
                uv.h[0] = *(const sv4*)(vr + voff[2 * c]);
                uv.h[1] = *(const sv4*)(vr + voff[2 * c + 1]);
                oA[mt] = MFMA(uv.s, pbA[c], oA[mt]);
                oB[mt] = MFMA(uv.s, pbB[c], oB[mt]);
            }
        }
        __builtin_amdgcn_s_setprio(0);
        __syncthreads();
    }

    float lA = laccA[0], lB = laccB[0];   // quad-uniform (full chunk sums)

    // ---- split-K merge: same fixed shift on both halves -> pure add
    float* Osh = SMEMf;
    float* Msh = SMEMf + 8704;   // reused for l
    if (kz == 1) {
        #pragma unroll
        for (int mt = 0; mt < 4; ++mt) {
            *(floatx4*)&Osh[(qw * 2 + 0) * 1088 + col * 68 + mt * 16 + quad * 4] = oA[mt];
            *(floatx4*)&Osh[(qw * 2 + 1) * 1088 + col * 68 + mt * 16 + quad * 4] = oB[mt];
        }
        if (quad == 0) {
            Msh[qw * 32 + col] = lA;
            Msh[qw * 32 + col + 16] = lB;
        }
    }
    __syncthreads();
    if (kz == 0) {
        float linvA = 1.0f / (lA + Msh[qw * 32 + col]);
        float linvB = 1.0f / (lB + Msh[qw * 32 + col + 16]);
        size_t rowA = (size_t)(b * 4096 + q0 + col) * 512 + h * 64;
        size_t rowB = rowA + (size_t)16 * 512;
        #pragma unroll
        for (int mt = 0; mt < 4; ++mt) {
            floatx4 o2A = *(const floatx4*)&Osh[(qw * 2 + 0) * 1088 + col * 68 + mt * 16 + quad * 4];
            floatx4 o2B = *(const floatx4*)&Osh[(qw * 2 + 1) * 1088 + col * 68 + mt * 16 + quad * 4];
            float w0 = (oA[mt][0] + o2A[0]) * linvA;
            float w1 = (oA[mt][1] + o2A[1]) * linvA;
            float w2 = (oA[mt][2] + o2A[2]) * linvA;
            float w3 = (oA[mt][3] + o2A[3]) * linvA;
            int2 hi, lo;
            hi.x = pack2(w0, w1); hi.y = pack2(w2, w3);
            lo.x = pack2(w0 - bf2f(f2bf(w0)), w1 - bf2f(f2bf(w1)));
            lo.y = pack2(w2 - bf2f(f2bf(w2)), w3 - bf2f(f2bf(w3)));
            *(int2*)(Ahi + rowA + mt * 16 + quad * 4) = hi;
            *(int2*)(Alo + rowA + mt * 16 + quad * 4) = lo;
            w0 = (oB[mt][0] + o2B[0]) * linvB;
            w1 = (oB[mt][1] + o2B[1]) * linvB;
            w2 = (oB[mt][2] + o2B[2]) * linvB;
            w3 = (oB[mt][3] + o2B[3]) * linvB;
            hi.x = pack2(w0, w1); hi.y = pack2(w2, w3);
            lo.x = pack2(w0 - bf2f(f2bf(w0)), w1 - bf2f(f2bf(w1)));
            lo.y = pack2(w2 - bf2f(f2bf(w2)), w3 - bf2f(f2bf(w3)));
            *(int2*)(Ahi + rowB + mt * 16 + quad * 4) = hi;
            *(int2*)(Alo + rowB + mt * 16 + quad * 4) = lo;
        }
    }
    #undef KOFF
    #undef VOFF
}

// ---------------------------------------------------------------- out GEMM
__global__ __launch_bounds__(256) void out_gemm(
    const short* __restrict__ Ahi, const short* __restrict__ Alo,
    const short* __restrict__ Whi, const short* __restrict__ Wlo,
    const float* __restrict__ bo, float* __restrict__ Out)
{
    __shared__ short SMEM[24576];                 // 48 KB
    #define AHS(bf) (SMEM + (bf) * 4096)
    #define ALS(bf) (SMEM + 8192 + (bf) * 4096)
    #define BHS(bf) (SMEM + 16384 + (bf) * 2048)
    #define BLS(bf) (SMEM + 20480 + (bf) * 2048)
    const int lane = threadIdx.x & 63, wave = threadIdx.x >> 6;
    const int col = lane & 15, quad = lane >> 4;
    const int wm = wave & 1, wn = wave >> 1;
    const int m0 = blockIdx.x * 128;
    const int n0 = blockIdx.y * 64;

    const int rl = lane >> 2, pch = lane & 3;
    const int lch = pch ^ (rl & 3) ^ ((rl >> 2) & 3);
    const int seg = wave * 2;
    const short* ah0 = Ahi + (size_t)(m0 + seg * 16 + rl) * 512 + lch * 8;
    const short* ah1 = ah0 + (size_t)16 * 512;
    const short* al0 = Alo + (size_t)(m0 + seg * 16 + rl) * 512 + lch * 8;
    const short* al1 = al0 + (size_t)16 * 512;
    const short* bh0 = Whi + (size_t)(n0 + wave * 16 + rl) * 512 + lch * 8;
    const short* bl0 = Wlo + (size_t)(n0 + wave * 16 + rl) * 512 + lch * 8;

    floatx4 acc[4][2] = {};

    GLDS16(ah0, AHS(0) + seg * 512);
    GLDS16(ah1, AHS(0) + (seg + 1) * 512);
    GLDS16(al0, ALS(0) + seg * 512);
    GLDS16(al1, ALS(0) + (seg + 1) * 512);
    GLDS16(bh0, BHS(0) + wave * 512);
    GLDS16(bl0, BLS(0) + wave * 512);
    __syncthreads();

    for (int t = 0; t < 16; ++t) {
        const int cur = t & 1;
        if (t < 15) {
            const int kb = (t + 1) * 32;
            GLDS16(ah0 + kb, AHS(cur ^ 1) + seg * 512);
            GLDS16(ah1 + kb, AHS(cur ^ 1) + (seg + 1) * 512);
            GLDS16(al0 + kb, ALS(cur ^ 1) + seg * 512);
            GLDS16(al1 + kb, ALS(cur ^ 1) + (seg + 1) * 512);
            GLDS16(bh0 + kb, BHS(cur ^ 1) + wave * 512);
            GLDS16(bl0 + kb, BLS(cur ^ 1) + wave * 512);
        }
        short8 ahf[4], alf[4], bhf[2], blf[2];
        #pragma unroll
        for (int it = 0; it < 4; ++it) {
            const int rA = wm * 64 + it * 16 + col;
            const int pA = quad ^ (rA & 3) ^ ((rA >> 2) & 3);
            ahf[it] = *(const short8*)(AHS(cur) + rA * 32 + pA * 8);
            alf[it] = *(const short8*)(ALS(cur) + rA * 32 + pA * 8);
        }
        #pragma unroll
        for (int jt = 0; jt < 2; ++jt) {
            const int rB = wn * 32 + jt * 16 + col;
            const int pB = quad ^ (rB & 3) ^ ((rB >> 2) & 3);
            bhf[jt] = *(const short8*)(BHS(cur) + rB * 32 + pB * 8);
            blf[jt] = *(const short8*)(BLS(cur) + rB * 32 + pB * 8);
        }
        #pragma unroll
        for (int i = 0; i < 4; ++i)
            #pragma unroll
            for (int j = 0; j < 2; ++j) {
                acc[i][j] = MFMA(ahf[i], bhf[j], acc[i][j]);
                acc[i][j] = MFMA(ahf[i], blf[j], acc[i][j]);
                acc[i][j] = MFMA(alf[i], bhf[j], acc[i][j]);
            }
        __syncthreads();
    }

    #pragma unroll
    for (int i = 0; i < 4; ++i)
        #pragma unroll
        for (int j = 0; j < 2; ++j)
            #pragma unroll
            for (int r = 0; r < 4; ++r) {
                int m = m0 + wm * 64 + i * 16 + quad * 4 + r;
                int n = n0 + wn * 32 + j * 16 + col;
                Out[(size_t)m * 512 + n] = acc[i][j][r] + bo[n];
            }
    #undef AHS
    #undef ALS
    #undef BHS
    #undef BLS
}

// ---------------------------------------------------------------- launcher
extern "C" void kernel_launch(void* const* d_in, const int* in_sizes, int n_in,
                              void* d_out, int out_size, void* d_ws, size_t ws_size,
                              hipStream_t stream) {
    (void)in_sizes; (void)n_in; (void)out_size; (void)ws_size;
    const float* x   = (const float*)d_in[0];
    const float* W_q = (const float*)d_in[1];
    const float* b_q = (const float*)d_in[2];
    const float* W_k = (const float*)d_in[3];
    const float* b_k = (const float*)d_in[4];
    const float* W_v = (const float*)d_in[5];
    const float* b_v = (const float*)d_in[6];
    const float* W_o = (const float*)d_in[7];
    const float* b_o = (const float*)d_in[8];
    float* out = (float*)d_out;
    char* ws = (char*)d_ws;

    short* Xb   = (short*)(ws + 0);          // 8192*512*2  = 8,388,608
    short* Wqb  = (short*)(ws + 8388608);
    short* Wkb  = (short*)(ws + 8912896);
    short* Wvb  = (short*)(ws + 9437184);
    short* Wohi = (short*)(ws + 9961472);
    short* Wolo = (short*)(ws + 10485760);
    short* Qb   = (short*)(ws + 11010048);   // [16][4096][64]
    short* Kb   = (short*)(ws + 19398656);
    short* VTb  = (short*)(ws + 27787264);   // [16][64][4096]
    short* Ahi  = (short*)(ws + 36175872);   // [8192][512]
    short* Alo  = (short*)(ws + 44564480);   // end 52,953,088 bytes

    cvt_bf16<<<dim3(2048), dim3(256), 0, stream>>>(x, Xb, 4194304);
    cvt3_bf16<<<dim3(384), dim3(256), 0, stream>>>(W_q, W_k, W_v, Wqb, Wkb, Wvb);
    cvt_split<<<dim3(128), dim3(256), 0, stream>>>(W_o, Wohi, Wolo, 262144);
    qkv_gemm<<<dim3(64, 12), dim3(256), 0, stream>>>(Xb, Wqb, Wkb, Wvb, b_q, b_k, b_v, Qb, Kb, VTb);
    flash_attn<<<dim3(512), dim3(512), 0, stream>>>(Qb, Kb, VTb, Ahi, Alo);
    out_gemm<<<dim3(64, 8), dim3(256), 0, stream>>>(Ahi, Alo, Wohi, Wolo, b_o, out);
}

// Round 5
// 196.316 us; speedup vs baseline: 1.0894x; 1.0894x over previous
//
#include <hip/hip_runtime.h>
#include <hip/hip_bf16.h>
#include <stdint.h>

// MultiheadSelfAttention: B=2, S=4096, D=512, H=8, HD=64
// v14: VALU diet round 2 (counter-driven: VALUBusy 53% is the roof).
//  (1) K-loop explicitly unrolled x2 with compile-time CUR: every LDS
//      read/write address folds to base-reg + offset: immediate; per-iter
//      address VALU ~eliminated.
//  (2) pack via inline-asm v_cvt_pk_bf16_f32 (builtin absent on gfx950;
//      the perm fallback was 3 VALU/pair -> 1).
//  (3) three convert kernels fused into one launch.
// v13's permuted-K=32 PV, raw v_exp, setprio retained. GEMMs unchanged.

typedef __attribute__((ext_vector_type(8))) short short8;
typedef __attribute__((ext_vector_type(4))) short sv4;
typedef __attribute__((ext_vector_type(4))) float floatx4;

#define MFMA(a, b, c) __builtin_amdgcn_mfma_f32_16x16x32_bf16((a), (b), (c), 0, 0, 0)

typedef __attribute__((address_space(1))) const void* gas_t;
typedef __attribute__((address_space(3))) void* las_t;
#define GLDS16(g, l) __builtin_amdgcn_global_load_lds((gas_t)(g), (las_t)(l), 16, 0, 0)

#define SM_SHIFT 13.0f

__device__ __forceinline__ float fexp2(float x) {
#if __has_builtin(__builtin_amdgcn_exp2f)
    return __builtin_amdgcn_exp2f(x);      // bare v_exp_f32
#else
    float r;
    asm("v_exp_f32 %0, %1" : "=v"(r) : "v"(x));
    return r;
#endif
}

__device__ __forceinline__ short f2bf(float f) {
    union { float f; uint32_t u; } c; c.f = f;
    uint32_t u = c.u;
    u += 0x7fffu + ((u >> 16) & 1u);   // RNE
    return (short)(u >> 16);
}
__device__ __forceinline__ float bf2f(short s) {
    union { float f; uint32_t u; } c; c.u = ((uint32_t)(uint16_t)s) << 16;
    return c.f;
}
__device__ __forceinline__ int pack2(float a, float b) {
    return (int)(uint16_t)f2bf(a) | ((int)(uint16_t)f2bf(b) << 16);
}
// bf16 pack of two floats: single v_cvt_pk_bf16_f32 (RNE) on gfx950.
__device__ __forceinline__ int pack2rn(float a, float b) {
#if __has_builtin(__builtin_amdgcn_cvt_pk_bf16_f32)
    auto r = __builtin_amdgcn_cvt_pk_bf16_f32(a, b);
    int out; __builtin_memcpy(&out, &r, 4);
    return out;
#else
    int r;
    asm("v_cvt_pk_bf16_f32 %0, %1, %2" : "=v"(r) : "v"(a), "v"(b));
    return r;
#endif
}

// ---------------------------------------------------------------- converts
// One kernel, three regions: x (2048 blocks), Wq/Wk/Wv (384), Wo split (128).
__global__ void cvt_all(const float* __restrict__ x,
                        const float* __restrict__ wq, const float* __restrict__ wk,
                        const float* __restrict__ wv, const float* __restrict__ wo,
                        short* __restrict__ xb, short* __restrict__ wqb,
                        short* __restrict__ wkb, short* __restrict__ wvb,
                        short* __restrict__ wohi, short* __restrict__ wolo)
{
    int bid = blockIdx.x;
    if (bid < 2048) {
        int i = (bid * 256 + threadIdx.x) * 8;
        floatx4 v0 = *(const floatx4*)(x + i);
        floatx4 v1 = *(const floatx4*)(x + i + 4);
        short8 o;
        #pragma unroll
        for (int j = 0; j < 4; ++j) { o[j] = f2bf(v0[j]); o[4 + j] = f2bf(v1[j]); }
        *(short8*)(xb + i) = o;
    } else if (bid < 2432) {
        int idx = (bid - 2048) * 256 + threadIdx.x;
        int which = idx >> 15;
        int i = (idx & 32767) * 8;
        const float* src = which == 0 ? wq : which == 1 ? wk : wv;
        short* dst = which == 0 ? wqb : which == 1 ? wkb : wvb;
        floatx4 v0 = *(const floatx4*)(src + i);
        floatx4 v1 = *(const floatx4*)(src + i + 4);
        short8 o;
        #pragma unroll
        for (int j = 0; j < 4; ++j) { o[j] = f2bf(v0[j]); o[4 + j] = f2bf(v1[j]); }
        *(short8*)(dst + i) = o;
    } else {
        int i = ((bid - 2432) * 256 + threadIdx.x) * 8;
        floatx4 v0 = *(const floatx4*)(wo + i);
        floatx4 v1 = *(const floatx4*)(wo + i + 4);
        short8 h, l;
        #pragma unroll
        for (int j = 0; j < 4; ++j) {
            short hh = f2bf(v0[j]); h[j] = hh; l[j] = f2bf(v0[j] - bf2f(hh));
            short hh1 = f2bf(v1[j]); h[4 + j] = hh1; l[4 + j] = f2bf(v1[j] - bf2f(hh1));
        }
        *(short8*)(wohi + i) = h;
        *(short8*)(wolo + i) = l;
    }
}

// ---------------------------------------------------------------- QKV GEMM
__global__ __launch_bounds__(256) void qkv_gemm(
    const short* __restrict__ Xb,
    const short* __restrict__ Wq, const short* __restrict__ Wk, const short* __restrict__ Wv,
    const float* __restrict__ bq, const float* __restrict__ bk, const float* __restrict__ bv,
    short* __restrict__ Qo, short* __restrict__ Ko, short* __restrict__ VTo)
{
    __shared__ short SMEM[16384];                 // 32 KB
    #define ASH(bf) (SMEM + (bf) * 4096)
    #define BSH(bf) (SMEM + 8192 + (bf) * 4096)
    const int lane = threadIdx.x & 63, wave = threadIdx.x >> 6;
    const int col = lane & 15, quad = lane >> 4;
    const int wm = wave & 1, wn = wave >> 1;
    const int m0 = blockIdx.x * 128;
    const int by = blockIdx.y;
    const int which = by >> 2;                    // 0=Q,1=K,2=V
    const int n0 = (by & 3) * 128;
    const short* W = which == 0 ? Wq : which == 1 ? Wk : Wv;
    const float* bias = which == 0 ? bq : which == 1 ? bk : bv;
    const float oscale = which == 0 ? 0.1803368801111204f : 1.0f;  // 0.125*log2e

    const int rl = lane >> 2, pch = lane & 3;
    const int lch = pch ^ (rl & 3) ^ ((rl >> 2) & 3);
    const int seg = wave * 2;
    const short* ag0 = Xb + (size_t)(m0 + seg * 16 + rl) * 512 + lch * 8;
    const short* ag1 = ag0 + (size_t)16 * 512;
    const short* bg0 = W + (size_t)(n0 + seg * 16 + rl) * 512 + lch * 8;
    const short* bg1 = bg0 + (size_t)16 * 512;

    floatx4 acc[4][4] = {};

    GLDS16(ag0, ASH(0) + seg * 512);
    GLDS16(ag1, ASH(0) + (seg + 1) * 512);
    GLDS16(bg0, BSH(0) + seg * 512);
    GLDS16(bg1, BSH(0) + (seg + 1) * 512);
    __syncthreads();

    for (int t = 0; t < 16; ++t) {
        const int cur = t & 1;
        if (t < 15) {
            const int kb = (t + 1) * 32;
            GLDS16(ag0 + kb, ASH(cur ^ 1) + seg * 512);
            GLDS16(ag1 + kb, ASH(cur ^ 1) + (seg + 1) * 512);
            GLDS16(bg0 + kb, BSH(cur ^ 1) + seg * 512);
            GLDS16(bg1 + kb, BSH(cur ^ 1) + (seg + 1) * 512);
        }
        short8 af[4], bf[4];
        #pragma unroll
        for (int it = 0; it < 4; ++it) {
            const int rA = wm * 64 + it * 16 + col;
            const int pA = quad ^ (rA & 3) ^ ((rA >> 2) & 3);
            af[it] = *(const short8*)(ASH(cur) + rA * 32 + pA * 8);
            const int rB = wn * 64 + it * 16 + col;
            const int pB = quad ^ (rB & 3) ^ ((rB >> 2) & 3);
            bf[it] = *(const short8*)(BSH(cur) + rB * 32 + pB * 8);
        }
        #pragma unroll
        for (int i = 0; i < 4; ++i)
            #pragma unroll
            for (int j = 0; j < 4; ++j)
                acc[i][j] = MFMA(af[i], bf[j], acc[i][j]);
        __syncthreads();
    }

    if (which < 2) {
        #pragma unroll
        for (int i = 0; i < 4; ++i)
            #pragma unroll
            for (int j = 0; j < 4; ++j)
                #pragma unroll
                for (int r = 0; r < 4; ++r) {
                    int m = m0 + wm * 64 + i * 16 + quad * 4 + r;
                    int n = n0 + wn * 64 + j * 16 + col;
                    float v = (acc[i][j][r] + bias[n]) * oscale;
                    int b = m >> 12, s = m & 4095;
                    int h = n >> 6, hd = n & 63;
                    int bh = b * 8 + h;
                    short bv16 = f2bf(v);
                    if (which == 0) Qo[((size_t)bh * 4096 + s) * 64 + hd] = bv16;
                    else            Ko[((size_t)bh * 4096 + s) * 64 + hd] = bv16;
                }
    } else {
        // V: per-wave LDS transpose (post-barrier, staging LDS is dead)
        short* tb = SMEM + wave * 4096;
        #pragma unroll
        for (int n2 = 0; n2 < 2; ++n2) {
            #pragma unroll
            for (int jj = 0; jj < 2; ++jj) {
                const int j = n2 * 2 + jj;
                const int n_rel = jj * 16 + col;
                const float bv_ = bias[n0 + wn * 64 + j * 16 + col];
                #pragma unroll
                for (int i = 0; i < 4; ++i) {
                    const int m_rel = i * 16 + quad * 4;
                    *(int*)(tb + n_rel * 72 + m_rel) =
                        pack2(acc[i][j][0] + bv_, acc[i][j][1] + bv_);
                    *(int*)(tb + n_rel * 72 + m_rel + 2) =
                        pack2(acc[i][j][2] + bv_, acc[i][j][3] + bv_);
                }
            }
            asm volatile("s_waitcnt lgkmcnt(0)" ::: "memory");  // wave-local
            const int n_rel = lane & 31, half = lane >> 5;
            const int n = n0 + wn * 64 + n2 * 32 + n_rel;
            const int h = n >> 6, hd = n & 63;
            const int bh = (m0 >> 12) * 8 + h;
            const int s0 = (m0 & 4095) + wm * 64 + half * 32;
            const short* src = tb + n_rel * 72 + half * 32;
            short* dst = VTo + ((size_t)bh * 64 + hd) * 4096 + s0;
            #pragma unroll
            for (int c = 0; c < 4; ++c)
                *(int4*)(dst + c * 8) = *(const int4*)(src + c * 8);
        }
    }
    #undef ASH
    #undef BSH
}

// ---------------------------------------------------------------- flash attn
// Fixed-shift softmax, permuted-k K=32 PV (v13). v14: loop unrolled x2 with
// compile-time CUR so all LDS addresses are base+imm; asm cvt_pk packs.
__device__ __forceinline__ void softmax_pk(
    const floatx4* sa, floatx4& lacc, short8 ones8, short8* pb)  // pb[2]
{
    #pragma unroll
    for (int c = 0; c < 2; ++c) {
        union { int i[4]; short8 s; } u;
        #pragma unroll
        for (int h = 0; h < 2; ++h) {          // nt = 2c+h
            float p0 = fexp2(sa[2 * c + h][0]);
            float p1 = fexp2(sa[2 * c + h][1]);
            float p2 = fexp2(sa[2 * c + h][2]);
            float p3 = fexp2(sa[2 * c + h][3]);
            u.i[2 * h]     = pack2rn(p0, p1);
            u.i[2 * h + 1] = pack2rn(p2, p3);
        }
        pb[c] = u.s;
        lacc = MFMA(ones8, u.s, lacc);   // l += column sums of this 32-k block
    }
}

__global__ __launch_bounds__(512, 4) void flash_attn(
    const short* __restrict__ Q, const short* __restrict__ Kk,
    const short* __restrict__ VT,
    short* __restrict__ Ahi, short* __restrict__ Alo)
{
    __shared__ float SMEMf[16384];               // 64 KB
    short* SMEM = (short*)SMEMf;
    const int lane = threadIdx.x & 63, wave = threadIdx.x >> 6;
    const int col = lane & 15, quad = lane >> 4;
    const int id = blockIdx.x;
    const int bh = (id & 7) * 2 + (id >> 8);     // 2 bh per XCD cluster
    const int bx = (id >> 3) & 31;
    const int b = bh >> 3, h = bh & 7;
    const int qw = wave & 3, kz = wave >> 2;
    const int q0 = bx * 128 + qw * 32;
    const int kbeg = kz * 2048;
    const size_t base = (size_t)bh * 4096 * 64;
    const size_t vbase = (size_t)bh * 64 * 4096;

    const short* qptr = Q + base + (size_t)(q0 + col) * 64 + quad * 8;
    short8 qA0 = *(const short8*)(qptr);
    short8 qA1 = *(const short8*)(qptr + 32);
    short8 qB0 = *(const short8*)(qptr + 16 * 64);
    short8 qB1 = *(const short8*)(qptr + 16 * 64 + 32);

    const int rloc = lane >> 3, pch = lane & 7;
    const int lch = pch ^ rloc;
    const short* kst0 = Kk + base + (size_t)(kbeg + qw * 16 + rloc) * 64 + lch * 8;
    const short* kst1 = kst0 + (size_t)8 * 64;
    const short* vst0 = VT + vbase + (size_t)(qw * 16 + rloc) * 4096 + kbeg + lch * 8;
    const short* vst1 = vst0 + (size_t)8 * 4096;

    floatx4 oA[4] = {}, oB[4] = {};
    floatx4 laccA = {0.f, 0.f, 0.f, 0.f}, laccB = {0.f, 0.f, 0.f, 0.f};
    const floatx4 mshift = {-SM_SHIFT, -SM_SHIFT, -SM_SHIFT, -SM_SHIFT};
    short8 ones8;
    #pragma unroll
    for (int j = 0; j < 8; ++j) ones8[j] = (short)0x3F80;   // bf16 1.0

    const int sw = col & 7;
    const int co0 = (quad ^ sw) * 8;
    const int co1 = ((quad + 4) ^ sw) * 8;
    int voff[4];
    #pragma unroll
    for (int nt = 0; nt < 4; ++nt)
        voff[nt] = ((2 * nt + (quad >> 1)) ^ sw) * 8 + (quad & 1) * 4;

    // Loop-invariant LDS bases (shorts). K tile f at kz*8192 + f*4096;
    // V tile f at 16384 + kz*8192 + f*4096. Reads fold to base + imm.
    const short* kb0 = SMEM + kz * 8192 + col * 64 + co0;
    const short* kb1 = SMEM + kz * 8192 + col * 64 + co1;
    const short* vb0 = SMEM + 16384 + kz * 8192 + col * 64 + voff[0];
    const short* vb1 = SMEM + 16384 + kz * 8192 + col * 64 + voff[1];
    const short* vb2 = SMEM + 16384 + kz * 8192 + col * 64 + voff[2];
    const short* vb3 = SMEM + 16384 + kz * 8192 + col * 64 + voff[3];
    short* const klds0 = SMEM + kz * 8192 + qw * 1024;
    short* const klds1 = klds0 + 4096;
    short* const vlds0 = SMEM + 16384 + kz * 8192 + qw * 1024;
    short* const vlds1 = vlds0 + 4096;

    {
        GLDS16(kst0, klds0);
        GLDS16(kst1, klds0 + 8 * 64);
        GLDS16(vst0, vlds0);
        GLDS16(vst1, vlds0 + 8 * 64);
    }
    __syncthreads();

#define FA_BODY(CUR, KO2, PF)                                                  \
    {                                                                          \
        if (PF) {                                                              \
            GLDS16(kst0 + (size_t)(KO2) * 64, (CUR) ? klds0 : klds1);          \
            GLDS16(kst1 + (size_t)(KO2) * 64, ((CUR) ? klds0 : klds1) + 512);  \
            GLDS16(vst0 + (KO2), (CUR) ? vlds0 : vlds1);                       \
            GLDS16(vst1 + (KO2), ((CUR) ? vlds0 : vlds1) + 512);               \
        }                                                                      \
        floatx4 saA[4], saB[4];                                                \
        __builtin_amdgcn_s_setprio(1);                                         \
        _Pragma("unroll")                                                      \
        for (int nt = 0; nt < 4; ++nt) {                                       \
            short8 k0 = *(const short8*)(kb0 + (CUR) * 4096 + nt * 1024);      \
            short8 k1 = *(const short8*)(kb1 + (CUR) * 4096 + nt * 1024);      \
            floatx4 z = MFMA(k0, qA0, mshift);                                 \
            saA[nt] = MFMA(k1, qA1, z);                                        \
            floatx4 z2 = MFMA(k0, qB0, mshift);                                \
            saB[nt] = MFMA(k1, qB1, z2);                                       \
        }                                                                      \
        __builtin_amdgcn_s_setprio(0);                                         \
        short8 pbA[2], pbB[2];                                                 \
        softmax_pk(saA, laccA, ones8, pbA);                                    \
        softmax_pk(saB, laccB, ones8, pbB);                                    \
        __builtin_amdgcn_s_setprio(1);                                         \
        _Pragma("unroll")                                                      \
        for (int mt = 0; mt < 4; ++mt) {                                       \
            union { sv4 h[2]; short8 s; } u0, u1;                              \
            u0.h[0] = *(const sv4*)(vb0 + (CUR) * 4096 + mt * 1024);           \
            u0.h[1] = *(const sv4*)(vb1 + (CUR) * 4096 + mt * 1024);           \
            u1.h[0] = *(const sv4*)(vb2 + (CUR) * 4096 + mt * 1024);           \
            u1.h[1] = *(const sv4*)(vb3 + (CUR) * 4096 + mt * 1024);           \
            oA[mt] = MFMA(u0.s, pbA[0], oA[mt]);                               \
            oB[mt] = MFMA(u0.s, pbB[0], oB[mt]);                               \
            oA[mt] = MFMA(u1.s, pbA[1], oA[mt]);                               \
            oB[mt] = MFMA(u1.s, pbB[1], oB[mt]);                               \
        }                                                                      \
        __builtin_amdgcn_s_setprio(0);                                         \
        __syncthreads();                                                       \
    }

    int ko2 = 64;
    for (int t2 = 0; t2 < 15; ++t2) {
        FA_BODY(0, ko2, 1); ko2 += 64;
        FA_BODY(1, ko2, 1); ko2 += 64;
    }
    FA_BODY(0, ko2, 1);
    FA_BODY(1, 0, 0);
#undef FA_BODY

    float lA = laccA[0], lB = laccB[0];   // quad-uniform (full chunk sums)

    // ---- split-K merge: same fixed shift on both halves -> pure add
    float* Osh = SMEMf;
    float* Msh = SMEMf + 8704;   // reused for l
    if (kz == 1) {
        #pragma unroll
        for (int mt = 0; mt < 4; ++mt) {
            *(floatx4*)&Osh[(qw * 2 + 0) * 1088 + col * 68 + mt * 16 + quad * 4] = oA[mt];
            *(floatx4*)&Osh[(qw * 2 + 1) * 1088 + col * 68 + mt * 16 + quad * 4] = oB[mt];
        }
        if (quad == 0) {
            Msh[qw * 32 + col] = lA;
            Msh[qw * 32 + col + 16] = lB;
        }
    }
    __syncthreads();
    if (kz == 0) {
        float linvA = 1.0f / (lA + Msh[qw * 32 + col]);
        float linvB = 1.0f / (lB + Msh[qw * 32 + col + 16]);
        size_t rowA = (size_t)(b * 4096 + q0 + col) * 512 + h * 64;
        size_t rowB = rowA + (size_t)16 * 512;
        #pragma unroll
        for (int mt = 0; mt < 4; ++mt) {
            floatx4 o2A = *(const floatx4*)&Osh[(qw * 2 + 0) * 1088 + col * 68 + mt * 16 + quad * 4];
            floatx4 o2B = *(const floatx4*)&Osh[(qw * 2 + 1) * 1088 + col * 68 + mt * 16 + quad * 4];
            float w0 = (oA[mt][0] + o2A[0]) * linvA;
            float w1 = (oA[mt][1] + o2A[1]) * linvA;
            float w2 = (oA[mt][2] + o2A[2]) * linvA;
            float w3 = (oA[mt][3] + o2A[3]) * linvA;
            int2 hi, lo;
            hi.x = pack2(w0, w1); hi.y = pack2(w2, w3);
            lo.x = pack2(w0 - bf2f(f2bf(w0)), w1 - bf2f(f2bf(w1)));
            lo.y = pack2(w2 - bf2f(f2bf(w2)), w3 - bf2f(f2bf(w3)));
            *(int2*)(Ahi + rowA + mt * 16 + quad * 4) = hi;
            *(int2*)(Alo + rowA + mt * 16 + quad * 4) = lo;
            w0 = (oB[mt][0] + o2B[0]) * linvB;
            w1 = (oB[mt][1] + o2B[1]) * linvB;
            w2 = (oB[mt][2] + o2B[2]) * linvB;
            w3 = (oB[mt][3] + o2B[3]) * linvB;
            hi.x = pack2(w0, w1); hi.y = pack2(w2, w3);
            lo.x = pack2(w0 - bf2f(f2bf(w0)), w1 - bf2f(f2bf(w1)));
            lo.y = pack2(w2 - bf2f(f2bf(w2)), w3 - bf2f(f2bf(w3)));
            *(int2*)(Ahi + rowB + mt * 16 + quad * 4) = hi;
            *(int2*)(Alo + rowB + mt * 16 + quad * 4) = lo;
        }
    }
}

// ---------------------------------------------------------------- out GEMM
__global__ __launch_bounds__(256) void out_gemm(
    const short* __restrict__ Ahi, const short* __restrict__ Alo,
    const short* __restrict__ Whi, const short* __restrict__ Wlo,
    const float* __restrict__ bo, float* __restrict__ Out)
{
    __shared__ short SMEM[24576];                 // 48 KB
    #define AHS(bf) (SMEM + (bf) * 4096)
    #define ALS(bf) (SMEM + 8192 + (bf) * 4096)
    #define BHS(bf) (SMEM + 16384 + (bf) * 2048)
    #define BLS(bf) (SMEM + 20480 + (bf) * 2048)
    const int lane = threadIdx.x & 63, wave = threadIdx.x >> 6;
    const int col = lane & 15, quad = lane >> 4;
    const int wm = wave & 1, wn = wave >> 1;
    const int m0 = blockIdx.x * 128;
    const int n0 = blockIdx.y * 64;

    const int rl = lane >> 2, pch = lane & 3;
    const int lch = pch ^ (rl & 3) ^ ((rl >> 2) & 3);
    const int seg = wave * 2;
    const short* ah0 = Ahi + (size_t)(m0 + seg * 16 + rl) * 512 + lch * 8;
    const short* ah1 = ah0 + (size_t)16 * 512;
    const short* al0 = Alo + (size_t)(m0 + seg * 16 + rl) * 512 + lch * 8;
    const short* al1 = al0 + (size_t)16 * 512;
    const short* bh0 = Whi + (size_t)(n0 + wave * 16 + rl) * 512 + lch * 8;
    const short* bl0 = Wlo + (size_t)(n0 + wave * 16 + rl) * 512 + lch * 8;

    floatx4 acc[4][2] = {};

    GLDS16(ah0, AHS(0) + seg * 512);
    GLDS16(ah1, AHS(0) + (seg + 1) * 512);
    GLDS16(al0, ALS(0) + seg * 512);
    GLDS16(al1, ALS(0) + (seg + 1) * 512);
    GLDS16(bh0, BHS(0) + wave * 512);
    GLDS16(bl0, BLS(0) + wave * 512);
    __syncthreads();

    for (int t = 0; t < 16; ++t) {
        const int cur = t & 1;
        if (t < 15) {
            const int kb = (t + 1) * 32;
            GLDS16(ah0 + kb, AHS(cur ^ 1) + seg * 512);
            GLDS16(ah1 + kb, AHS(cur ^ 1) + (seg + 1) * 512);
            GLDS16(al0 + kb, ALS(cur ^ 1) + seg * 512);
            GLDS16(al1 + kb, ALS(cur ^ 1) + (seg + 1) * 512);
            GLDS16(bh0 + kb, BHS(cur ^ 1) + wave * 512);
            GLDS16(bl0 + kb, BLS(cur ^ 1) + wave * 512);
        }
        short8 ahf[4], alf[4], bhf[2], blf[2];
        #pragma unroll
        for (int it = 0; it < 4; ++it) {
            const int rA = wm * 64 + it * 16 + col;
            const int pA = quad ^ (rA & 3) ^ ((rA >> 2) & 3);
            ahf[it] = *(const short8*)(AHS(cur) + rA * 32 + pA * 8);
            alf[it] = *(const short8*)(ALS(cur) + rA * 32 + pA * 8);
        }
        #pragma unroll
        for (int jt = 0; jt < 2; ++jt) {
            const int rB = wn * 32 + jt * 16 + col;
            const int pB = quad ^ (rB & 3) ^ ((rB >> 2) & 3);
            bhf[jt] = *(const short8*)(BHS(cur) + rB * 32 + pB * 8);
            blf[jt] = *(const short8*)(BLS(cur) + rB * 32 + pB * 8);
        }
        #pragma unroll
        for (int i = 0; i < 4; ++i)
            #pragma unroll
            for (int j = 0; j < 2; ++j) {
                acc[i][j] = MFMA(ahf[i], bhf[j], acc[i][j]);
                acc[i][j] = MFMA(ahf[i], blf[j], acc[i][j]);
                acc[i][j] = MFMA(alf[i], bhf[j], acc[i][j]);
            }
        __syncthreads();
    }

    #pragma unroll
    for (int i = 0; i < 4; ++i)
        #pragma unroll
        for (int j = 0; j < 2; ++j)
            #pragma unroll
            for (int r = 0; r < 4; ++r) {
                int m = m0 + wm * 64 + i * 16 + quad * 4 + r;
                int n = n0 + wn * 32 + j * 16 + col;
                Out[(size_t)m * 512 + n] = acc[i][j][r] + bo[n];
            }
    #undef AHS
    #undef ALS
    #undef BHS
    #undef BLS
}

// ---------------------------------------------------------------- launcher
extern "C" void kernel_launch(void* const* d_in, const int* in_sizes, int n_in,
                              void* d_out, int out_size, void* d_ws, size_t ws_size,
                              hipStream_t stream) {
    (void)in_sizes; (void)n_in; (void)out_size; (void)ws_size;
    const float* x   = (const float*)d_in[0];
    const float* W_q = (const float*)d_in[1];
    const float* b_q = (const float*)d_in[2];
    const float* W_k = (const float*)d_in[3];
    const float* b_k = (const float*)d_in[4];
    const float* W_v = (const float*)d_in[5];
    const float* b_v = (const float*)d_in[6];
    const float* W_o = (const float*)d_in[7];
    const float* b_o = (const float*)d_in[8];
    float* out = (float*)d_out;
    char* ws = (char*)d_ws;

    short* Xb   = (short*)(ws + 0);          // 8192*512*2  = 8,388,608
    short* Wqb  = (short*)(ws + 8388608);
    short* Wkb  = (short*)(ws + 8912896);
    short* Wvb  = (short*)(ws + 9437184);
    short* Wohi = (short*)(ws + 9961472);
    short* Wolo = (short*)(ws + 10485760);
    short* Qb   = (short*)(ws + 11010048);   // [16][4096][64]
    short* Kb   = (short*)(ws + 19398656);
    short* VTb  = (short*)(ws + 27787264);   // [16][64][4096]
    short* Ahi  = (short*)(ws + 36175872);   // [8192][512]
    short* Alo  = (short*)(ws + 44564480);   // end 52,953,088 bytes

    cvt_all<<<dim3(2560), dim3(256), 0, stream>>>(x, W_q, W_k, W_v, W_o,
                                                  Xb, Wqb, Wkb, Wvb, Wohi, Wolo);
    qkv_gemm<<<dim3(64, 12), dim3(256), 0, stream>>>(Xb, Wqb, Wkb, Wvb, b_q, b_k, b_v, Qb, Kb, VTb);
    flash_attn<<<dim3(512), dim3(512), 0, stream>>>(Qb, Kb, VTb, Ahi, Alo);
    out_gemm<<<dim3(64, 8), dim3(256), 0, stream>>>(Ahi, Alo, Wohi, Wolo, b_o, out);
}

// Round 6
// 184.470 us; speedup vs baseline: 1.1594x; 1.0642x over previous
//
#include <hip/hip_runtime.h>
#include <hip/hip_bf16.h>
#include <stdint.h>

// MultiheadSelfAttention: B=2, S=4096, D=512, H=8, HD=64
// v15: LDS-traffic diet on flash.
//  (1) 64 q-rows per wave (4 q-tiles): each K/V LDS fragment feeds 4 MFMAs
//      instead of 2 -> LDS bytes/instr per unit work halved; barriers per
//      work halved. Block = 256 q rows, grid = 256 (1 block/CU).
//  (2) V stored key-PERMUTED in VT (p = 32c+8q+4h+j for k = 32c+16h+4q+j)
//      at the qkv epilogue, so flash's PV A-fragment is ONE ds_read_b128
//      matching pb's positional key layout (was 2x ds_read_b64).
// v12-v14 techniques retained (raw v_exp, asm cvt_pk, setprio, unrolled CUR,
// permuted-k K=32 PV). out_gemm/cvt unchanged.

typedef __attribute__((ext_vector_type(8))) short short8;
typedef __attribute__((ext_vector_type(4))) short sv4;
typedef __attribute__((ext_vector_type(4))) float floatx4;

#define MFMA(a, b, c) __builtin_amdgcn_mfma_f32_16x16x32_bf16((a), (b), (c), 0, 0, 0)

typedef __attribute__((address_space(1))) const void* gas_t;
typedef __attribute__((address_space(3))) void* las_t;
#define GLDS16(g, l) __builtin_amdgcn_global_load_lds((gas_t)(g), (las_t)(l), 16, 0, 0)

#define SM_SHIFT 13.0f

__device__ __forceinline__ float fexp2(float x) {
#if __has_builtin(__builtin_amdgcn_exp2f)
    return __builtin_amdgcn_exp2f(x);      // bare v_exp_f32
#else
    float r;
    asm("v_exp_f32 %0, %1" : "=v"(r) : "v"(x));
    return r;
#endif
}

__device__ __forceinline__ short f2bf(float f) {
    union { float f; uint32_t u; } c; c.f = f;
    uint32_t u = c.u;
    u += 0x7fffu + ((u >> 16) & 1u);   // RNE
    return (short)(u >> 16);
}
__device__ __forceinline__ float bf2f(short s) {
    union { float f; uint32_t u; } c; c.u = ((uint32_t)(uint16_t)s) << 16;
    return c.f;
}
__device__ __forceinline__ int pack2(float a, float b) {
    return (int)(uint16_t)f2bf(a) | ((int)(uint16_t)f2bf(b) << 16);
}
__device__ __forceinline__ int pack2rn(float a, float b) {
#if __has_builtin(__builtin_amdgcn_cvt_pk_bf16_f32)
    auto r = __builtin_amdgcn_cvt_pk_bf16_f32(a, b);
    int out; __builtin_memcpy(&out, &r, 4);
    return out;
#else
    int r;
    asm("v_cvt_pk_bf16_f32 %0, %1, %2" : "=v"(r) : "v"(a), "v"(b));
    return r;
#endif
}

// ---------------------------------------------------------------- converts
__global__ void cvt_all(const float* __restrict__ x,
                        const float* __restrict__ wq, const float* __restrict__ wk,
                        const float* __restrict__ wv, const float* __restrict__ wo,
                        short* __restrict__ xb, short* __restrict__ wqb,
                        short* __restrict__ wkb, short* __restrict__ wvb,
                        short* __restrict__ wohi, short* __restrict__ wolo)
{
    int bid = blockIdx.x;
    if (bid < 2048) {
        int i = (bid * 256 + threadIdx.x) * 8;
        floatx4 v0 = *(const floatx4*)(x + i);
        floatx4 v1 = *(const floatx4*)(x + i + 4);
        short8 o;
        #pragma unroll
        for (int j = 0; j < 4; ++j) { o[j] = f2bf(v0[j]); o[4 + j] = f2bf(v1[j]); }
        *(short8*)(xb + i) = o;
    } else if (bid < 2432) {
        int idx = (bid - 2048) * 256 + threadIdx.x;
        int which = idx >> 15;
        int i = (idx & 32767) * 8;
        const float* src = which == 0 ? wq : which == 1 ? wk : wv;
        short* dst = which == 0 ? wqb : which == 1 ? wkb : wvb;
        floatx4 v0 = *(const floatx4*)(src + i);
        floatx4 v1 = *(const floatx4*)(src + i + 4);
        short8 o;
        #pragma unroll
        for (int j = 0; j < 4; ++j) { o[j] = f2bf(v0[j]); o[4 + j] = f2bf(v1[j]); }
        *(short8*)(dst + i) = o;
    } else {
        int i = ((bid - 2432) * 256 + threadIdx.x) * 8;
        floatx4 v0 = *(const floatx4*)(wo + i);
        floatx4 v1 = *(const floatx4*)(wo + i + 4);
        short8 h, l;
        #pragma unroll
        for (int j = 0; j < 4; ++j) {
            short hh = f2bf(v0[j]); h[j] = hh; l[j] = f2bf(v0[j] - bf2f(hh));
            short hh1 = f2bf(v1[j]); h[4 + j] = hh1; l[4 + j] = f2bf(v1[j] - bf2f(hh1));
        }
        *(short8*)(wohi + i) = h;
        *(short8*)(wolo + i) = l;
    }
}

// ---------------------------------------------------------------- QKV GEMM
__global__ __launch_bounds__(256) void qkv_gemm(
    const short* __restrict__ Xb,
    const short* __restrict__ Wq, const short* __restrict__ Wk, const short* __restrict__ Wv,
    const float* __restrict__ bq, const float* __restrict__ bk, const float* __restrict__ bv,
    short* __restrict__ Qo, short* __restrict__ Ko, short* __restrict__ VTo)
{
    __shared__ short SMEM[16384];                 // 32 KB
    #define ASH(bf) (SMEM + (bf) * 4096)
    #define BSH(bf) (SMEM + 8192 + (bf) * 4096)
    const int lane = threadIdx.x & 63, wave = threadIdx.x >> 6;
    const int col = lane & 15, quad = lane >> 4;
    const int wm = wave & 1, wn = wave >> 1;
    const int m0 = blockIdx.x * 128;
    const int by = blockIdx.y;
    const int which = by >> 2;                    // 0=Q,1=K,2=V
    const int n0 = (by & 3) * 128;
    const short* W = which == 0 ? Wq : which == 1 ? Wk : Wv;
    const float* bias = which == 0 ? bq : which == 1 ? bk : bv;
    const float oscale = which == 0 ? 0.1803368801111204f : 1.0f;  // 0.125*log2e

    const int rl = lane >> 2, pch = lane & 3;
    const int lch = pch ^ (rl & 3) ^ ((rl >> 2) & 3);
    const int seg = wave * 2;
    const short* ag0 = Xb + (size_t)(m0 + seg * 16 + rl) * 512 + lch * 8;
    const short* ag1 = ag0 + (size_t)16 * 512;
    const short* bg0 = W + (size_t)(n0 + seg * 16 + rl) * 512 + lch * 8;
    const short* bg1 = bg0 + (size_t)16 * 512;

    floatx4 acc[4][4] = {};

    GLDS16(ag0, ASH(0) + seg * 512);
    GLDS16(ag1, ASH(0) + (seg + 1) * 512);
    GLDS16(bg0, BSH(0) + seg * 512);
    GLDS16(bg1, BSH(0) + (seg + 1) * 512);
    __syncthreads();

    for (int t = 0; t < 16; ++t) {
        const int cur = t & 1;
        if (t < 15) {
            const int kb = (t + 1) * 32;
            GLDS16(ag0 + kb, ASH(cur ^ 1) + seg * 512);
            GLDS16(ag1 + kb, ASH(cur ^ 1) + (seg + 1) * 512);
            GLDS16(bg0 + kb, BSH(cur ^ 1) + seg * 512);
            GLDS16(bg1 + kb, BSH(cur ^ 1) + (seg + 1) * 512);
        }
        short8 af[4], bf[4];
        #pragma unroll
        for (int it = 0; it < 4; ++it) {
            const int rA = wm * 64 + it * 16 + col;
            const int pA = quad ^ (rA & 3) ^ ((rA >> 2) & 3);
            af[it] = *(const short8*)(ASH(cur) + rA * 32 + pA * 8);
            const int rB = wn * 64 + it * 16 + col;
            const int pB = quad ^ (rB & 3) ^ ((rB >> 2) & 3);
            bf[it] = *(const short8*)(BSH(cur) + rB * 32 + pB * 8);
        }
        #pragma unroll
        for (int i = 0; i < 4; ++i)
            #pragma unroll
            for (int j = 0; j < 4; ++j)
                acc[i][j] = MFMA(af[i], bf[j], acc[i][j]);
        __syncthreads();
    }

    if (which < 2) {
        #pragma unroll
        for (int i = 0; i < 4; ++i)
            #pragma unroll
            for (int j = 0; j < 4; ++j)
                #pragma unroll
                for (int r = 0; r < 4; ++r) {
                    int m = m0 + wm * 64 + i * 16 + quad * 4 + r;
                    int n = n0 + wn * 64 + j * 16 + col;
                    float v = (acc[i][j][r] + bias[n]) * oscale;
                    int b = m >> 12, s = m & 4095;
                    int h = n >> 6, hd = n & 63;
                    int bh = b * 8 + h;
                    short bv16 = f2bf(v);
                    if (which == 0) Qo[((size_t)bh * 4096 + s) * 64 + hd] = bv16;
                    else            Ko[((size_t)bh * 4096 + s) * 64 + hd] = bv16;
                }
    } else {
        // V: per-wave LDS transpose, then key-PERMUTED store within each
        // 64-key block: dest p = 32c + 8q + 4h + j for key k = 32c+16h+4q+j.
        // Flash's PV A-fragment is then one contiguous 16B read.
        short* tb = SMEM + wave * 4096;
        #pragma unroll
        for (int n2 = 0; n2 < 2; ++n2) {
            #pragma unroll
            for (int jj = 0; jj < 2; ++jj) {
                const int j = n2 * 2 + jj;
                const int n_rel = jj * 16 + col;
                const float bv_ = bias[n0 + wn * 64 + j * 16 + col];
                #pragma unroll
                for (int i = 0; i < 4; ++i) {
                    const int m_rel = i * 16 + quad * 4;
                    *(int*)(tb + n_rel * 72 + m_rel) =
                        pack2(acc[i][j][0] + bv_, acc[i][j][1] + bv_);
                    *(int*)(tb + n_rel * 72 + m_rel + 2) =
                        pack2(acc[i][j][2] + bv_, acc[i][j][3] + bv_);
                }
            }
            asm volatile("s_waitcnt lgkmcnt(0)" ::: "memory");  // wave-local
            const int n_rel = lane & 31, half = lane >> 5;
            const int n = n0 + wn * 64 + n2 * 32 + n_rel;
            const int h = n >> 6, hd = n & 63;
            const int bh = (m0 >> 12) * 8 + h;
            const int s0 = (m0 & 4095) + wm * 64 + half * 32;   // 32-aligned; c = half
            const short* src = tb + n_rel * 72 + half * 32;
            short* dst = VTo + ((size_t)bh * 64 + hd) * 4096 + s0;
            #pragma unroll
            for (int qq = 0; qq < 4; ++qq) {
                union { sv4 hh[2]; int4 v; } u;
                u.hh[0] = *(const sv4*)(src + 4 * qq);        // h=0: keys 4q+0..3
                u.hh[1] = *(const sv4*)(src + 16 + 4 * qq);   // h=1: keys 16+4q+0..3
                *(int4*)(dst + qq * 8) = u.v;
            }
        }
    }
    #undef ASH
    #undef BSH
}

// ---------------------------------------------------------------- flash attn
// 8 waves = 4 qw x 2 kz; each wave owns 64 q-rows (4 q-tiles of 16).
// Fixed-shift softmax (QK^T seeded C=-13), permuted-k K=32 PV, l via
// ones-MFMA. One barrier per 64-key tile.
__global__ __launch_bounds__(512, 2) void flash_attn(
    const short* __restrict__ Q, const short* __restrict__ Kk,
    const short* __restrict__ VT,
    short* __restrict__ Ahi, short* __restrict__ Alo)
{
    __shared__ float SMEMf[16384];               // 64 KB
    short* SMEM = (short*)SMEMf;
    const int lane = threadIdx.x & 63, wave = threadIdx.x >> 6;
    const int col = lane & 15, quad = lane >> 4;
    const int id = blockIdx.x;
    const int bh = id & 15;      // same-bh blocks have id stride 16 -> same XCD (id%8)
    const int bx = id >> 4;
    const int b = bh >> 3, h = bh & 7;
    const int qw = wave & 3, kz = wave >> 2;
    const int q0 = bx * 256 + qw * 64;
    const int kbeg = kz * 2048;
    const size_t base = (size_t)bh * 4096 * 64;
    const size_t vbase = (size_t)bh * 64 * 4096;

    short8 qf0[4], qf1[4];
    #pragma unroll
    for (int qt = 0; qt < 4; ++qt) {
        const short* qp = Q + base + (size_t)(q0 + qt * 16 + col) * 64 + quad * 8;
        qf0[qt] = *(const short8*)(qp);
        qf1[qt] = *(const short8*)(qp + 32);
    }

    const int rloc = lane >> 3, pch = lane & 7;
    const int lch = pch ^ rloc;
    const short* kst0 = Kk + base + (size_t)(kbeg + qw * 16 + rloc) * 64 + lch * 8;
    const short* kst1 = kst0 + (size_t)8 * 64;
    const short* vst0 = VT + vbase + (size_t)(qw * 16 + rloc) * 4096 + kbeg + lch * 8;
    const short* vst1 = vst0 + (size_t)8 * 4096;

    floatx4 o[4][4] = {};                         // [qt][mt]
    floatx4 lacc[4] = {};
    const floatx4 mshift = {-SM_SHIFT, -SM_SHIFT, -SM_SHIFT, -SM_SHIFT};
    short8 ones8;
    #pragma unroll
    for (int j = 0; j < 8; ++j) ones8[j] = (short)0x3F80;   // bf16 1.0

    const int sw = col & 7;
    const int co0 = (quad ^ sw) * 8;
    const int co1 = ((quad + 4) ^ sw) * 8;
    // V read chunk for group c: global chunk 4c+quad, swizzled by row&7==sw.
    // co0/co1 coincide with c=0 / c=1 chunk offsets.
    const short* kb0 = SMEM + kz * 8192 + col * 64 + co0;
    const short* kb1 = SMEM + kz * 8192 + col * 64 + co1;
    const short* vb0 = SMEM + 16384 + kz * 8192 + col * 64 + co0;
    const short* vb1 = SMEM + 16384 + kz * 8192 + col * 64 + co1;
    short* const klds0 = SMEM + kz * 8192 + qw * 1024;
    short* const klds1 = klds0 + 4096;
    short* const vlds0 = SMEM + 16384 + kz * 8192 + qw * 1024;
    short* const vlds1 = vlds0 + 4096;

    GLDS16(kst0, klds0);
    GLDS16(kst1, klds0 + 512);
    GLDS16(vst0, vlds0);
    GLDS16(vst1, vlds0 + 512);
    __syncthreads();

#define FA_BODY(CUR, KO2, PF)                                                  \
    {                                                                          \
        if (PF) {                                                              \
            GLDS16(kst0 + (size_t)(KO2) * 64, (CUR) ? klds0 : klds1);          \
            GLDS16(kst1 + (size_t)(KO2) * 64, ((CUR) ? klds0 : klds1) + 512);  \
            GLDS16(vst0 + (KO2), (CUR) ? vlds0 : vlds1);                       \
            GLDS16(vst1 + (KO2), ((CUR) ? vlds0 : vlds1) + 512);               \
        }                                                                      \
        _Pragma("unroll")                                                      \
        for (int c = 0; c < 2; ++c) {                                          \
            short8 k0a = *(const short8*)(kb0 + (CUR) * 4096 + (2 * c) * 1024);     \
            short8 k1a = *(const short8*)(kb1 + (CUR) * 4096 + (2 * c) * 1024);     \
            short8 k0b = *(const short8*)(kb0 + (CUR) * 4096 + (2 * c + 1) * 1024); \
            short8 k1b = *(const short8*)(kb1 + (CUR) * 4096 + (2 * c + 1) * 1024); \
            floatx4 saA[4], saB[4];                                            \
            __builtin_amdgcn_s_setprio(1);                                     \
            _Pragma("unroll")                                                  \
            for (int qt = 0; qt < 4; ++qt) {                                   \
                floatx4 z = MFMA(k0a, qf0[qt], mshift);                        \
                saA[qt] = MFMA(k1a, qf1[qt], z);                               \
                floatx4 z2 = MFMA(k0b, qf0[qt], mshift);                       \
                saB[qt] = MFMA(k1b, qf1[qt], z2);                              \
            }                                                                  \
            __builtin_amdgcn_s_setprio(0);                                     \
            short8 pb[4];                                                      \
            _Pragma("unroll")                                                  \
            for (int qt = 0; qt < 4; ++qt) {                                   \
                union { int i[4]; short8 s; } u;                               \
                u.i[0] = pack2rn(fexp2(saA[qt][0]), fexp2(saA[qt][1]));        \
                u.i[1] = pack2rn(fexp2(saA[qt][2]), fexp2(saA[qt][3]));        \
                u.i[2] = pack2rn(fexp2(saB[qt][0]), fexp2(saB[qt][1]));        \
                u.i[3] = pack2rn(fexp2(saB[qt][2]), fexp2(saB[qt][3]));        \
                pb[qt] = u.s;                                                  \
                lacc[qt] = MFMA(ones8, u.s, lacc[qt]);                         \
            }                                                                  \
            __builtin_amdgcn_s_setprio(1);                                     \
            _Pragma("unroll")                                                  \
            for (int mt = 0; mt < 4; ++mt) {                                   \
                const short8 vv = *(const short8*)(((c) ? vb1 : vb0) + (CUR) * 4096 + mt * 1024); \
                o[0][mt] = MFMA(vv, pb[0], o[0][mt]);                          \
                o[1][mt] = MFMA(vv, pb[1], o[1][mt]);                          \
                o[2][mt] = MFMA(vv, pb[2], o[2][mt]);                          \
                o[3][mt] = MFMA(vv, pb[3], o[3][mt]);                          \
            }                                                                  \
            __builtin_amdgcn_s_setprio(0);                                     \
        }                                                                      \
        __syncthreads();                                                       \
    }

    int ko2 = 64;
    for (int t2 = 0; t2 < 15; ++t2) {
        FA_BODY(0, ko2, 1); ko2 += 64;
        FA_BODY(1, ko2, 1); ko2 += 64;
    }
    FA_BODY(0, ko2, 1);
    FA_BODY(1, 0, 0);
#undef FA_BODY

    // ---- split-K merge, two passes of 2 q-tiles (Osh footprint reused)
    float* Osh = SMEMf;
    float* Msh = SMEMf + 8704;
    #pragma unroll
    for (int p = 0; p < 2; ++p) {
        const int ta = 2 * p, tb_ = 2 * p + 1;
        if (kz == 1) {
            #pragma unroll
            for (int mt = 0; mt < 4; ++mt) {
                *(floatx4*)&Osh[(qw * 2 + 0) * 1088 + col * 68 + mt * 16 + quad * 4] = o[ta][mt];
                *(floatx4*)&Osh[(qw * 2 + 1) * 1088 + col * 68 + mt * 16 + quad * 4] = o[tb_][mt];
            }
            if (quad == 0) {
                Msh[qw * 32 + col] = lacc[ta][0];
                Msh[qw * 32 + col + 16] = lacc[tb_][0];
            }
        }
        __syncthreads();
        if (kz == 0) {
            float linvA = 1.0f / (lacc[ta][0] + Msh[qw * 32 + col]);
            float linvB = 1.0f / (lacc[tb_][0] + Msh[qw * 32 + col + 16]);
            size_t rowA = (size_t)(b * 4096 + q0 + ta * 16 + col) * 512 + h * 64;
            size_t rowB = rowA + (size_t)16 * 512;
            #pragma unroll
            for (int mt = 0; mt < 4; ++mt) {
                floatx4 o2A = *(const floatx4*)&Osh[(qw * 2 + 0) * 1088 + col * 68 + mt * 16 + quad * 4];
                floatx4 o2B = *(const floatx4*)&Osh[(qw * 2 + 1) * 1088 + col * 68 + mt * 16 + quad * 4];
                float w0 = (o[ta][mt][0] + o2A[0]) * linvA;
                float w1 = (o[ta][mt][1] + o2A[1]) * linvA;
                float w2 = (o[ta][mt][2] + o2A[2]) * linvA;
                float w3 = (o[ta][mt][3] + o2A[3]) * linvA;
                int2 hi, lo;
                hi.x = pack2(w0, w1); hi.y = pack2(w2, w3);
                lo.x = pack2(w0 - bf2f(f2bf(w0)), w1 - bf2f(f2bf(w1)));
                lo.y = pack2(w2 - bf2f(f2bf(w2)), w3 - bf2f(f2bf(w3)));
                *(int2*)(Ahi + rowA + mt * 16 + quad * 4) = hi;
                *(int2*)(Alo + rowA + mt * 16 + quad * 4) = lo;
                w0 = (o[tb_][mt][0] + o2B[0]) * linvB;
                w1 = (o[tb_][mt][1] + o2B[1]) * linvB;
                w2 = (o[tb_][mt][2] + o2B[2]) * linvB;
                w3 = (o[tb_][mt][3] + o2B[3]) * linvB;
                hi.x = pack2(w0, w1); hi.y = pack2(w2, w3);
                lo.x = pack2(w0 - bf2f(f2bf(w0)), w1 - bf2f(f2bf(w1)));
                lo.y = pack2(w2 - bf2f(f2bf(w2)), w3 - bf2f(f2bf(w3)));
                *(int2*)(Ahi + rowB + mt * 16 + quad * 4) = hi;
                *(int2*)(Alo + rowB + mt * 16 + quad * 4) = lo;
            }
        }
        __syncthreads();
    }
}

// ---------------------------------------------------------------- out GEMM
__global__ __launch_bounds__(256) void out_gemm(
    const short* __restrict__ Ahi, const short* __restrict__ Alo,
    const short* __restrict__ Whi, const short* __restrict__ Wlo,
    const float* __restrict__ bo, float* __restrict__ Out)
{
    __shared__ short SMEM[24576];                 // 48 KB
    #define AHS(bf) (SMEM + (bf) * 4096)
    #define ALS(bf) (SMEM + 8192 + (bf) * 4096)
    #define BHS(bf) (SMEM + 16384 + (bf) * 2048)
    #define BLS(bf) (SMEM + 20480 + (bf) * 2048)
    const int lane = threadIdx.x & 63, wave = threadIdx.x >> 6;
    const int col = lane & 15, quad = lane >> 4;
    const int wm = wave & 1, wn = wave >> 1;
    const int m0 = blockIdx.x * 128;
    const int n0 = blockIdx.y * 64;

    const int rl = lane >> 2, pch = lane & 3;
    const int lch = pch ^ (rl & 3) ^ ((rl >> 2) & 3);
    const int seg = wave * 2;
    const short* ah0 = Ahi + (size_t)(m0 + seg * 16 + rl) * 512 + lch * 8;
    const short* ah1 = ah0 + (size_t)16 * 512;
    const short* al0 = Alo + (size_t)(m0 + seg * 16 + rl) * 512 + lch * 8;
    const short* al1 = al0 + (size_t)16 * 512;
    const short* bh0 = Whi + (size_t)(n0 + wave * 16 + rl) * 512 + lch * 8;
    const short* bl0 = Wlo + (size_t)(n0 + wave * 16 + rl) * 512 + lch * 8;

    floatx4 acc[4][2] = {};

    GLDS16(ah0, AHS(0) + seg * 512);
    GLDS16(ah1, AHS(0) + (seg + 1) * 512);
    GLDS16(al0, ALS(0) + seg * 512);
    GLDS16(al1, ALS(0) + (seg + 1) * 512);
    GLDS16(bh0, BHS(0) + wave * 512);
    GLDS16(bl0, BLS(0) + wave * 512);
    __syncthreads();

    for (int t = 0; t < 16; ++t) {
        const int cur = t & 1;
        if (t < 15) {
            const int kb = (t + 1) * 32;
            GLDS16(ah0 + kb, AHS(cur ^ 1) + seg * 512);
            GLDS16(ah1 + kb, AHS(cur ^ 1) + (seg + 1) * 512);
            GLDS16(al0 + kb, ALS(cur ^ 1) + seg * 512);
            GLDS16(al1 + kb, ALS(cur ^ 1) + (seg + 1) * 512);
            GLDS16(bh0 + kb, BHS(cur ^ 1) + wave * 512);
            GLDS16(bl0 + kb, BLS(cur ^ 1) + wave * 512);
        }
        short8 ahf[4], alf[4], bhf[2], blf[2];
        #pragma unroll
        for (int it = 0; it < 4; ++it) {
            const int rA = wm * 64 + it * 16 + col;
            const int pA = quad ^ (rA & 3) ^ ((rA >> 2) & 3);
            ahf[it] = *(const short8*)(AHS(cur) + rA * 32 + pA * 8);
            alf[it] = *(const short8*)(ALS(cur) + rA * 32 + pA * 8);
        }
        #pragma unroll
        for (int jt = 0; jt < 2; ++jt) {
            const int rB = wn * 32 + jt * 16 + col;
            const int pB = quad ^ (rB & 3) ^ ((rB >> 2) & 3);
            bhf[jt] = *(const short8*)(BHS(cur) + rB * 32 + pB * 8);
            blf[jt] = *(const short8*)(BLS(cur) + rB * 32 + pB * 8);
        }
        #pragma unroll
        for (int i = 0; i < 4; ++i)
            #pragma unroll
            for (int j = 0; j < 2; ++j) {
                acc[i][j] = MFMA(ahf[i], bhf[j], acc[i][j]);
                acc[i][j] = MFMA(ahf[i], blf[j], acc[i][j]);
                acc[i][j] = MFMA(alf[i], bhf[j], acc[i][j]);
            }
        __syncthreads();
    }

    #pragma unroll
    for (int i = 0; i < 4; ++i)
        #pragma unroll
        for (int j = 0; j < 2; ++j)
            #pragma unroll
            for (int r = 0; r < 4; ++r) {
                int m = m0 + wm * 64 + i * 16 + quad * 4 + r;
                int n = n0 + wn * 32 + j * 16 + col;
                Out[(size_t)m * 512 + n] = acc[i][j][r] + bo[n];
            }
    #undef AHS
    #undef ALS
    #undef BHS
    #undef BLS
}

// ---------------------------------------------------------------- launcher
extern "C" void kernel_launch(void* const* d_in, const int* in_sizes, int n_in,
                              void* d_out, int out_size, void* d_ws, size_t ws_size,
                              hipStream_t stream) {
    (void)in_sizes; (void)n_in; (void)out_size; (void)ws_size;
    const float* x   = (const float*)d_in[0];
    const float* W_q = (const float*)d_in[1];
    const float* b_q = (const float*)d_in[2];
    const float* W_k = (const float*)d_in[3];
    const float* b_k = (const float*)d_in[4];
    const float* W_v = (const float*)d_in[5];
    const float* b_v = (const float*)d_in[6];
    const float* W_o = (const float*)d_in[7];
    const float* b_o = (const float*)d_in[8];
    float* out = (float*)d_out;
    char* ws = (char*)d_ws;

    short* Xb   = (short*)(ws + 0);          // 8192*512*2  = 8,388,608
    short* Wqb  = (short*)(ws + 8388608);
    short* Wkb  = (short*)(ws + 8912896);
    short* Wvb  = (short*)(ws + 9437184);
    short* Wohi = (short*)(ws + 9961472);
    short* Wolo = (short*)(ws + 10485760);
    short* Qb   = (short*)(ws + 11010048);   // [16][4096][64]
    short* Kb   = (short*)(ws + 19398656);
    short* VTb  = (short*)(ws + 27787264);   // [16][64][4096] (key-permuted per 64-block)
    short* Ahi  = (short*)(ws + 36175872);   // [8192][512]
    short* Alo  = (short*)(ws + 44564480);   // end 52,953,088 bytes

    cvt_all<<<dim3(2560), dim3(256), 0, stream>>>(x, W_q, W_k, W_v, W_o,
                                                  Xb, Wqb, Wkb, Wvb, Wohi, Wolo);
    qkv_gemm<<<dim3(64, 12), dim3(256), 0, stream>>>(Xb, Wqb, Wkb, Wvb, b_q, b_k, b_v, Qb, Kb, VTb);
    flash_attn<<<dim3(256), dim3(512), 0, stream>>>(Qb, Kb, VTb, Ahi, Alo);
    out_gemm<<<dim3(64, 8), dim3(256), 0, stream>>>(Ahi, Alo, Wohi, Wolo, b_o, out);
}